// Round 10
// baseline (299.652 us; speedup 1.0000x reference)
//
#include <hip/hip_runtime.h>
#include <hip/hip_fp16.h>
#include <math.h>

#define NN 100000
#define NE 1600000
#define NBUK 391        // ceil(NN/256) buckets of 256 dst nodes
#define CAP 4608        // per-bucket region capacity (avg 4096, +8 sigma)
#define EPB 4096        // edges per phase-B block

__device__ __forceinline__ float leaky02(float v) {
    return v > 0.0f ? v : 0.2f * v;
}

// ---------------- CSR build via LDS radix (no device-random atomics) --------

__global__ __launch_bounds__(256) void k_bucket(
    const int* __restrict__ src, const int* __restrict__ dst,
    int* __restrict__ bucketCnt, int* __restrict__ gBuf)
{
    __shared__ int stg[EPB];
    __shared__ int tgt[EPB];
    __shared__ int lcnt[NBUK];
    __shared__ int lexc[NBUK];
    __shared__ int lgb[NBUK];
    __shared__ int totalLocal;
    const int t = threadIdx.x;
    const int e0 = blockIdx.x * EPB;

    for (int i = t; i < NBUK; i += 256) lcnt[i] = 0;
    __syncthreads();

    int bk[16], pk[16];
    #pragma unroll
    for (int j = 0; j < 16; ++j) {
        const int e = e0 + j * 256 + t;
        if (e < NE) {
            const int d = dst[e];
            bk[j] = d >> 8;
            pk[j] = (src[e] << 8) | (d & 255);
            atomicAdd(&lcnt[bk[j]], 1);
        } else bk[j] = -1;
    }
    __syncthreads();

    if (t < 64) {
        int carry = 0;
        for (int c = 0; c < NBUK; c += 64) {
            const int idx = c + t;
            int v = (idx < NBUK) ? lcnt[idx] : 0;
            int inc = v;
            #pragma unroll
            for (int off = 1; off < 64; off <<= 1) {
                int u = __shfl_up(inc, off, 64);
                if (t >= off) inc += u;
            }
            if (idx < NBUK) lexc[idx] = carry + inc - v;
            carry += __shfl(inc, 63, 64);
        }
        if (t == 0) totalLocal = carry;
    }
    __syncthreads();

    for (int i = t; i < NBUK; i += 256) {
        const int c = lcnt[i];
        lgb[i] = c ? atomicAdd(&bucketCnt[i], c) : 0;
        lcnt[i] = 0;
    }
    __syncthreads();

    #pragma unroll
    for (int j = 0; j < 16; ++j) {
        if (bk[j] >= 0) {
            const int r = atomicAdd(&lcnt[bk[j]], 1);
            const int p = lexc[bk[j]] + r;
            stg[p] = pk[j];
            int slot = lgb[bk[j]] + r;
            if (slot >= CAP) slot = CAP - 1;   // statistically impossible
            tgt[p] = bk[j] * CAP + slot;
        }
    }
    __syncthreads();

    const int tot = totalLocal;
    for (int i = t; i < tot; i += 256)
        gBuf[tgt[i]] = stg[i];
}

// Phase C: per bucket, compute own global base (prefix over bucketCnt),
// counting-sort by dst&255 in LDS, emit row_ptr + ssrc (streaming writes).
__global__ __launch_bounds__(256) void k_csr_local(
    const int* __restrict__ bucketCnt, const int* __restrict__ gBuf,
    int* __restrict__ row_ptr, int* __restrict__ ssrc)
{
    __shared__ int stg2[CAP];
    __shared__ int stg3[CAP];
    __shared__ int c2[256];
    __shared__ int sc[256];
    __shared__ int red[256];
    const int t = threadIdx.x;
    const int k = blockIdx.x;
    const int cnt = min(bucketCnt[k], CAP);

    int part = 0;
    for (int j = t; j < k; j += 256) part += bucketCnt[j];
    red[t] = part;
    __syncthreads();
    for (int s2 = 128; s2; s2 >>= 1) {
        if (t < s2) red[t] += red[t + s2];
        __syncthreads();
    }
    const int gb = red[0];

    c2[t] = 0;
    __syncthreads();
    for (int i = t; i < cnt; i += 256) {
        const int pk = gBuf[k * CAP + i];
        stg2[i] = pk;
        atomicAdd(&c2[pk & 255], 1);
    }
    __syncthreads();
    if (t < 64) {
        int carry = 0;
        for (int c = 0; c < 256; c += 64) {
            int v = c2[c + t];
            int inc = v;
            #pragma unroll
            for (int off = 1; off < 64; off <<= 1) {
                int u = __shfl_up(inc, off, 64);
                if (t >= off) inc += u;
            }
            sc[c + t] = carry + inc - v;
            carry += __shfl(inc, 63, 64);
        }
    }
    __syncthreads();
    const int node = (k << 8) + t;
    if (node < NN) row_ptr[node] = gb + sc[t];
    if (k == NBUK - 1 && t == 0) row_ptr[NN] = NE;
    c2[t] = 0;
    __syncthreads();
    for (int i = t; i < cnt; i += 256) {
        const int pk = stg2[i];
        const int dl = pk & 255;
        const int r = atomicAdd(&c2[dl], 1);
        stg3[sc[dl] + r] = pk >> 8;
    }
    __syncthreads();
    for (int i = t; i < cnt; i += 256)
        ssrc[gb + i] = stg3[i];
}

// ---------------- Layer 0 prep (H=4, D=16, F=64) ----------------

// GEMM z = x@W (fp16 out) + attention coeffs. W column in 64 VGPRs per lane;
// x rows loaded via the SCALAR pipe (wave-uniform address -> s_load).
__global__ __launch_bounds__(256) void k_node_prep(
    const float* __restrict__ xin, const float* __restrict__ W,
    const float* __restrict__ al, const float* __restrict__ ar,
    __half* __restrict__ z, float* __restrict__ el, float* __restrict__ er)
{
    const int t = threadIdx.x;
    const int lane = t & 63;
    const int wvU = __builtin_amdgcn_readfirstlane(t >> 6);   // uniform wave id
    const int nodeBase = blockIdx.x * 64 + wvU * 16;

    float wc[64];
    #pragma unroll
    for (int k = 0; k < 64; ++k) wc[k] = W[k * 64 + lane];
    const float a_l = al[lane], a_r = ar[lane];

    #pragma unroll 1
    for (int i = 0; i < 16; i += 2) {
        const int nA = nodeBase + i;
        if (nA >= NN) break;                       // uniform branch
        const int nB = nA + 1;
        const bool hasB = (nB < NN);
        const float4* __restrict__ xA4 = (const float4*)(xin + (size_t)nA * 64);
        const float4* __restrict__ xB4 = (const float4*)(xin + (size_t)(hasB ? nB : nA) * 64);

        float accA = 0.f, accB = 0.f;
        #pragma unroll
        for (int k4 = 0; k4 < 16; ++k4) {
            const float4 a4 = xA4[k4];
            const float4 b4 = xB4[k4];
            const float w0 = wc[k4 * 4 + 0], w1 = wc[k4 * 4 + 1];
            const float w2 = wc[k4 * 4 + 2], w3 = wc[k4 * 4 + 3];
            accA += a4.x * w0 + a4.y * w1 + a4.z * w2 + a4.w * w3;
            accB += b4.x * w0 + b4.y * w1 + b4.z * w2 + b4.w * w3;
        }

        {
            z[(size_t)nA * 64 + lane] = __float2half(accA);
            float pl = accA * a_l, pr = accA * a_r;
            #pragma unroll
            for (int off = 8; off > 0; off >>= 1) {
                pl += __shfl_xor(pl, off, 16);
                pr += __shfl_xor(pr, off, 16);
            }
            if ((lane & 15) == 0) {
                const int h = lane >> 4;
                el[nA * 4 + h] = pl;
                er[nA * 4 + h] = pr;
            }
        }
        if (hasB) {
            z[(size_t)nB * 64 + lane] = __float2half(accB);
            float pl = accB * a_l, pr = accB * a_r;
            #pragma unroll
            for (int off = 8; off > 0; off >>= 1) {
                pl += __shfl_xor(pl, off, 16);
                pr += __shfl_xor(pr, off, 16);
            }
            if ((lane & 15) == 0) {
                const int h = lane >> 4;
                el[nB * 4 + h] = pl;
                er[nB * 4 + h] = pr;
            }
        }
    }
}

// ---------------- Aggregation gather core (shared) ----------------
// Subgroup sg owns edges beg+sg, beg+sg+4, ...; unroll x4 -> 16 z-rows in
// flight per wave. Returns combined acc (quad sl) and den (head sl>>2) on
// every lane.
__device__ __forceinline__ void agg_gather(
    const int beg, const int end, const int sg, const int sl, const int hh,
    const float er_hh, const int* __restrict__ ssrc,
    const float* __restrict__ el, const __half* __restrict__ z,
    float4& acc, float& den)
{
    acc = make_float4(0.f, 0.f, 0.f, 0.f);
    den = 0.f;
    int i = beg + sg;
    for (; i + 12 < end; i += 16) {
        const int s0 = ssrc[i], s1 = ssrc[i + 4];
        const int s2 = ssrc[i + 8], s3 = ssrc[i + 12];
        const float x0 = __expf(leaky02(el[s0 * 4 + hh] + er_hh));
        const float x1 = __expf(leaky02(el[s1 * 4 + hh] + er_hh));
        const float x2 = __expf(leaky02(el[s2 * 4 + hh] + er_hh));
        const float x3 = __expf(leaky02(el[s3 * 4 + hh] + er_hh));
        const uint2 r0 = *(const uint2*)(z + (size_t)s0 * 64 + sl * 4);
        const uint2 r1 = *(const uint2*)(z + (size_t)s1 * 64 + sl * 4);
        const uint2 r2 = *(const uint2*)(z + (size_t)s2 * 64 + sl * 4);
        const uint2 r3 = *(const uint2*)(z + (size_t)s3 * 64 + sl * 4);
        den += (x0 + x1) + (x2 + x3);
        float2 p;
        p = __half22float2(*(const __half2*)&r0.x); acc.x += x0 * p.x; acc.y += x0 * p.y;
        p = __half22float2(*(const __half2*)&r0.y); acc.z += x0 * p.x; acc.w += x0 * p.y;
        p = __half22float2(*(const __half2*)&r1.x); acc.x += x1 * p.x; acc.y += x1 * p.y;
        p = __half22float2(*(const __half2*)&r1.y); acc.z += x1 * p.x; acc.w += x1 * p.y;
        p = __half22float2(*(const __half2*)&r2.x); acc.x += x2 * p.x; acc.y += x2 * p.y;
        p = __half22float2(*(const __half2*)&r2.y); acc.z += x2 * p.x; acc.w += x2 * p.y;
        p = __half22float2(*(const __half2*)&r3.x); acc.x += x3 * p.x; acc.y += x3 * p.y;
        p = __half22float2(*(const __half2*)&r3.y); acc.z += x3 * p.x; acc.w += x3 * p.y;
    }
    for (; i < end; i += 4) {
        const int s0 = ssrc[i];
        const float x0 = __expf(leaky02(el[s0 * 4 + hh] + er_hh));
        const uint2 r0 = *(const uint2*)(z + (size_t)s0 * 64 + sl * 4);
        den += x0;
        float2 p;
        p = __half22float2(*(const __half2*)&r0.x); acc.x += x0 * p.x; acc.y += x0 * p.y;
        p = __half22float2(*(const __half2*)&r0.y); acc.z += x0 * p.x; acc.w += x0 * p.y;
    }
    #pragma unroll
    for (int off = 16; off < 64; off <<= 1) {
        acc.x += __shfl_xor(acc.x, off, 64);
        acc.y += __shfl_xor(acc.y, off, 64);
        acc.z += __shfl_xor(acc.z, off, 64);
        acc.w += __shfl_xor(acc.w, off, 64);
        den   += __shfl_xor(den,   off, 64);
    }
}

// Layer-0 agg fused with layer-1 prep: after combine, every lane has the full
// aggregated vector (quad sl replicated); lane l computes next-layer column l
// via 16 quad-broadcasts against a preloaded W1 column. Writes z1 (fp16) +
// el1/er1 directly -- no xA round-trip, no separate prep dispatch.
// Grid 6250, 4 waves, 4 nodes per wave.
__global__ __launch_bounds__(256) void k_csr_agg_fuse(
    const int* __restrict__ row_ptr, const int* __restrict__ ssrc,
    const float* __restrict__ el, const float* __restrict__ er,
    const __half* __restrict__ z, const float* __restrict__ b,
    const float* __restrict__ Wn, const float* __restrict__ aln,
    const float* __restrict__ arn,
    __half* __restrict__ zn, float* __restrict__ eln, float* __restrict__ ern)
{
    const int t = threadIdx.x;
    const int wv = t >> 6, l = t & 63;
    const int sg = l >> 4, sl = l & 15, hh = sl >> 2;

    float wcol[64];
    #pragma unroll
    for (int k = 0; k < 64; ++k) wcol[k] = Wn[k * 64 + l];
    const float a_l = aln[l], a_r = arn[l];
    const float4 b4 = *(const float4*)(b + sl * 4);

    #pragma unroll 1
    for (int it = 0; it < 4; ++it) {
        const int n = blockIdx.x * 16 + wv * 4 + it;
        const int beg = row_ptr[n], end = row_ptr[n + 1];
        const float er_hh = er[n * 4 + hh];
        float4 acc; float den;
        agg_gather(beg, end, sg, sl, hh, er_hh, ssrc, el, z, acc, den);
        const float dinv = 1.0f / fmaxf(den, 1e-9f);
        float4 v;
        v.x = fmaxf(acc.x * dinv + b4.x, 0.f);
        v.y = fmaxf(acc.y * dinv + b4.y, 0.f);
        v.z = fmaxf(acc.z * dinv + b4.z, 0.f);
        v.w = fmaxf(acc.w * dinv + b4.w, 0.f);

        // GEMV: lane l owns next-layer column l
        float zacc = 0.f;
        #pragma unroll
        for (int q = 0; q < 16; ++q) {
            const float vx = __shfl(v.x, q, 64);
            const float vy = __shfl(v.y, q, 64);
            const float vz = __shfl(v.z, q, 64);
            const float vw = __shfl(v.w, q, 64);
            zacc += vx * wcol[4 * q + 0] + vy * wcol[4 * q + 1]
                  + vz * wcol[4 * q + 2] + vw * wcol[4 * q + 3];
        }
        zn[(size_t)n * 64 + l] = __float2half(zacc);
        float pl = zacc * a_l, pr = zacc * a_r;
        #pragma unroll
        for (int off = 8; off > 0; off >>= 1) {
            pl += __shfl_xor(pl, off, 16);
            pr += __shfl_xor(pr, off, 16);
        }
        if (sl == 0) {
            eln[n * 4 + (l >> 4)] = pl;
            ern[n * 4 + (l >> 4)] = pr;
        }
    }
}

// Layer-1 agg fused with output GEMV (Wo) -> zo[n].
__global__ __launch_bounds__(256) void k_csr_agg_out(
    const int* __restrict__ row_ptr, const int* __restrict__ ssrc,
    const float* __restrict__ el, const float* __restrict__ er,
    const __half* __restrict__ z, const float* __restrict__ b,
    const float* __restrict__ Wo, float* __restrict__ zo)
{
    const int t = threadIdx.x;
    const int wv = t >> 6, l = t & 63;
    const int sg = l >> 4, sl = l & 15, hh = sl >> 2;
    const float4 b4 = *(const float4*)(b + sl * 4);
    const float4 w4 = *(const float4*)(Wo + sl * 4);

    #pragma unroll 1
    for (int it = 0; it < 4; ++it) {
        const int n = blockIdx.x * 16 + wv * 4 + it;
        const int beg = row_ptr[n], end = row_ptr[n + 1];
        const float er_hh = er[n * 4 + hh];
        float4 acc; float den;
        agg_gather(beg, end, sg, sl, hh, er_hh, ssrc, el, z, acc, den);
        const float dinv = 1.0f / fmaxf(den, 1e-9f);
        float4 v;
        v.x = fmaxf(acc.x * dinv + b4.x, 0.f);
        v.y = fmaxf(acc.y * dinv + b4.y, 0.f);
        v.z = fmaxf(acc.z * dinv + b4.z, 0.f);
        v.w = fmaxf(acc.w * dinv + b4.w, 0.f);
        float p = v.x * w4.x + v.y * w4.y + v.z * w4.z + v.w * w4.w;
        #pragma unroll
        for (int off = 1; off < 16; off <<= 1) p += __shfl_xor(p, off, 64);
        if (l == 0) zo[n] = p;
    }
}

// ---------------- Output layer (H=1, D=1), single-pass, 16 lanes/node -------

__global__ __launch_bounds__(256) void k_csr_agg_o(
    const int* __restrict__ row_ptr, const int* __restrict__ ssrc,
    const float* __restrict__ zo, const float* __restrict__ alo,
    const float* __restrict__ aro, const float* __restrict__ bo,
    float* __restrict__ out)
{
    const int t = threadIdx.x, l = t & 15;
    const int n = blockIdx.x * 16 + (t >> 4);
    const float a = alo[0];
    const float zr = aro[0] * zo[n];
    const int beg = row_ptr[n], end = row_ptr[n + 1];

    float den = 0.f, accv = 0.f;
    for (int i = beg + l; i < end; i += 16) {
        const float zs = zo[ssrc[i]];
        const float ex = __expf(leaky02(a * zs + zr));
        den += ex; accv += ex * zs;
    }
    #pragma unroll
    for (int off = 8; off; off >>= 1) {
        den  += __shfl_xor(den, off, 16);
        accv += __shfl_xor(accv, off, 16);
    }
    if (l == 0) out[n] = accv / fmaxf(den, 1e-9f) + bo[0];
}

// ---------------- Launch ----------------

extern "C" void kernel_launch(void* const* d_in, const int* in_sizes, int n_in,
                              void* d_out, int out_size, void* d_ws, size_t ws_size,
                              hipStream_t stream) {
    const float* feat = (const float*)d_in[0];
    const int*   src  = (const int*)d_in[1];
    const int*   dst  = (const int*)d_in[2];
    const float* W0   = (const float*)d_in[3];
    const float* al0  = (const float*)d_in[4];
    const float* ar0  = (const float*)d_in[5];
    const float* b0   = (const float*)d_in[6];
    const float* W1   = (const float*)d_in[7];
    const float* al1  = (const float*)d_in[8];
    const float* ar1  = (const float*)d_in[9];
    const float* b1   = (const float*)d_in[10];
    const float* Wo   = (const float*)d_in[11];
    const float* alo  = (const float*)d_in[12];
    const float* aro  = (const float*)d_in[13];
    const float* bo   = (const float*)d_in[14];
    float* out = (float*)d_out;

    // workspace carve-up
    int* bucketCnt  = (int*)d_ws;                   // [NBUK] (zeroed)
    int* row_ptr    = bucketCnt + NBUK;             // [NN+1]
    int* gBuf       = row_ptr + (NN + 2);           // [NBUK*CAP]
    int* ssrc       = gBuf + (size_t)NBUK * CAP;    // [NE]
    uintptr_t pa = ((uintptr_t)(ssrc + NE) + 15) & ~(uintptr_t)15;
    __half* zA = (__half*)pa;                       // [NN*64] fp16
    __half* zB = zA + (size_t)NN * 64;              // [NN*64] fp16
    float* el0 = (float*)(zB + (size_t)NN * 64);    // [NN*4]
    float* er0 = el0 + (size_t)NN * 4;              // [NN*4]
    float* el1 = er0 + (size_t)NN * 4;              // [NN*4]
    float* er1 = el1 + (size_t)NN * 4;              // [NN*4]
    float* zo  = er1 + (size_t)NN * 4;              // [NN]

    const int gBkt  = (NE + EPB - 1) / EPB;  // 391
    const int gPrep = (NN + 63) / 64;        // 1563
    const int gN16  = NN / 16;               // 6250
    const int gAgg  = NN / 16;               // 6250 (4 nodes/wave)

    // CSR build (LDS radix, 2 kernels + memset)
    hipMemsetAsync(bucketCnt, 0, NBUK * sizeof(int), stream);
    k_bucket   <<<gBkt, 256, 0, stream>>>(src, dst, bucketCnt, gBuf);
    k_csr_local<<<NBUK, 256, 0, stream>>>(bucketCnt, gBuf, row_ptr, ssrc);

    // Layer 0 prep: feat -> zA, el0, er0
    k_node_prep<<<gPrep, 256, 0, stream>>>(feat, W0, al0, ar0, zA, el0, er0);

    // Layer-0 agg + fused layer-1 prep: -> zB, el1, er1
    k_csr_agg_fuse<<<gAgg, 256, 0, stream>>>(row_ptr, ssrc, el0, er0, zA, b0,
                                             W1, al1, ar1, zB, el1, er1);

    // Layer-1 agg + fused output GEMV: -> zo
    k_csr_agg_out<<<gAgg, 256, 0, stream>>>(row_ptr, ssrc, el1, er1, zB, b1,
                                            Wo, zo);

    // Output layer
    k_csr_agg_o<<<gN16, 256, 0, stream>>>(row_ptr, ssrc, zo, alo, aro, bo, out);
}

// Round 11
// 275.628 us; speedup vs baseline: 1.0872x; 1.0872x over previous
//
#include <hip/hip_runtime.h>
#include <hip/hip_fp16.h>
#include <math.h>

#define NN 100000
#define NE 1600000
#define NBUK 391        // ceil(NN/256) buckets of 256 dst nodes
#define CAP 4608        // per-bucket region capacity (avg 4096, +8 sigma)
#define EPB 4096        // edges per phase-B block

__device__ __forceinline__ float leaky02(float v) {
    return v > 0.0f ? v : 0.2f * v;
}

// ---------------- CSR build via LDS radix (no device-random atomics) --------

__global__ __launch_bounds__(256) void k_bucket(
    const int* __restrict__ src, const int* __restrict__ dst,
    int* __restrict__ bucketCnt, int* __restrict__ gBuf)
{
    __shared__ int stg[EPB];
    __shared__ int tgt[EPB];
    __shared__ int lcnt[NBUK];
    __shared__ int lexc[NBUK];
    __shared__ int lgb[NBUK];
    __shared__ int totalLocal;
    const int t = threadIdx.x;
    const int e0 = blockIdx.x * EPB;

    for (int i = t; i < NBUK; i += 256) lcnt[i] = 0;
    __syncthreads();

    int bk[16], pk[16];
    #pragma unroll
    for (int j = 0; j < 16; ++j) {
        const int e = e0 + j * 256 + t;
        if (e < NE) {
            const int d = dst[e];
            bk[j] = d >> 8;
            pk[j] = (src[e] << 8) | (d & 255);
            atomicAdd(&lcnt[bk[j]], 1);
        } else bk[j] = -1;
    }
    __syncthreads();

    if (t < 64) {
        int carry = 0;
        for (int c = 0; c < NBUK; c += 64) {
            const int idx = c + t;
            int v = (idx < NBUK) ? lcnt[idx] : 0;
            int inc = v;
            #pragma unroll
            for (int off = 1; off < 64; off <<= 1) {
                int u = __shfl_up(inc, off, 64);
                if (t >= off) inc += u;
            }
            if (idx < NBUK) lexc[idx] = carry + inc - v;
            carry += __shfl(inc, 63, 64);
        }
        if (t == 0) totalLocal = carry;
    }
    __syncthreads();

    for (int i = t; i < NBUK; i += 256) {
        const int c = lcnt[i];
        lgb[i] = c ? atomicAdd(&bucketCnt[i], c) : 0;
        lcnt[i] = 0;
    }
    __syncthreads();

    #pragma unroll
    for (int j = 0; j < 16; ++j) {
        if (bk[j] >= 0) {
            const int r = atomicAdd(&lcnt[bk[j]], 1);
            const int p = lexc[bk[j]] + r;
            stg[p] = pk[j];
            int slot = lgb[bk[j]] + r;
            if (slot >= CAP) slot = CAP - 1;   // statistically impossible
            tgt[p] = bk[j] * CAP + slot;
        }
    }
    __syncthreads();

    const int tot = totalLocal;
    for (int i = t; i < tot; i += 256)
        gBuf[tgt[i]] = stg[i];
}

// Phase C: per bucket, compute own global base (prefix over bucketCnt),
// counting-sort by dst&255 in LDS, emit row_ptr + ssrc (streaming writes).
__global__ __launch_bounds__(256) void k_csr_local(
    const int* __restrict__ bucketCnt, const int* __restrict__ gBuf,
    int* __restrict__ row_ptr, int* __restrict__ ssrc)
{
    __shared__ int stg2[CAP];
    __shared__ int stg3[CAP];
    __shared__ int c2[256];
    __shared__ int sc[256];
    __shared__ int red[256];
    const int t = threadIdx.x;
    const int k = blockIdx.x;
    const int cnt = min(bucketCnt[k], CAP);

    int part = 0;
    for (int j = t; j < k; j += 256) part += bucketCnt[j];
    red[t] = part;
    __syncthreads();
    for (int s2 = 128; s2; s2 >>= 1) {
        if (t < s2) red[t] += red[t + s2];
        __syncthreads();
    }
    const int gb = red[0];

    c2[t] = 0;
    __syncthreads();
    for (int i = t; i < cnt; i += 256) {
        const int pk = gBuf[k * CAP + i];
        stg2[i] = pk;
        atomicAdd(&c2[pk & 255], 1);
    }
    __syncthreads();
    if (t < 64) {
        int carry = 0;
        for (int c = 0; c < 256; c += 64) {
            int v = c2[c + t];
            int inc = v;
            #pragma unroll
            for (int off = 1; off < 64; off <<= 1) {
                int u = __shfl_up(inc, off, 64);
                if (t >= off) inc += u;
            }
            sc[c + t] = carry + inc - v;
            carry += __shfl(inc, 63, 64);
        }
    }
    __syncthreads();
    const int node = (k << 8) + t;
    if (node < NN) row_ptr[node] = gb + sc[t];
    if (k == NBUK - 1 && t == 0) row_ptr[NN] = NE;
    c2[t] = 0;
    __syncthreads();
    for (int i = t; i < cnt; i += 256) {
        const int pk = stg2[i];
        const int dl = pk & 255;
        const int r = atomicAdd(&c2[dl], 1);
        stg3[sc[dl] + r] = pk >> 8;
    }
    __syncthreads();
    for (int i = t; i < cnt; i += 256)
        ssrc[gb + i] = stg3[i];
}

// ---------------- Layer prep (H=4, D=16, F=64) ----------------

// GEMM z = x@W (fp16 out) + attention coeffs. W column in 64 VGPRs per lane;
// x rows loaded via the SCALAR pipe (wave-uniform address -> s_load).
__global__ __launch_bounds__(256) void k_node_prep(
    const float* __restrict__ xin, const float* __restrict__ W,
    const float* __restrict__ al, const float* __restrict__ ar,
    __half* __restrict__ z, float* __restrict__ el, float* __restrict__ er)
{
    const int t = threadIdx.x;
    const int lane = t & 63;
    const int wvU = __builtin_amdgcn_readfirstlane(t >> 6);   // uniform wave id
    const int nodeBase = blockIdx.x * 64 + wvU * 16;

    float wc[64];
    #pragma unroll
    for (int k = 0; k < 64; ++k) wc[k] = W[k * 64 + lane];
    const float a_l = al[lane], a_r = ar[lane];

    #pragma unroll 1
    for (int i = 0; i < 16; i += 2) {
        const int nA = nodeBase + i;
        if (nA >= NN) break;                       // uniform branch
        const int nB = nA + 1;
        const bool hasB = (nB < NN);
        const float4* __restrict__ xA4 = (const float4*)(xin + (size_t)nA * 64);
        const float4* __restrict__ xB4 = (const float4*)(xin + (size_t)(hasB ? nB : nA) * 64);

        float accA = 0.f, accB = 0.f;
        #pragma unroll
        for (int k4 = 0; k4 < 16; ++k4) {
            const float4 a4 = xA4[k4];
            const float4 b4 = xB4[k4];
            const float w0 = wc[k4 * 4 + 0], w1 = wc[k4 * 4 + 1];
            const float w2 = wc[k4 * 4 + 2], w3 = wc[k4 * 4 + 3];
            accA += a4.x * w0 + a4.y * w1 + a4.z * w2 + a4.w * w3;
            accB += b4.x * w0 + b4.y * w1 + b4.z * w2 + b4.w * w3;
        }

        {
            z[(size_t)nA * 64 + lane] = __float2half(accA);
            float pl = accA * a_l, pr = accA * a_r;
            #pragma unroll
            for (int off = 8; off > 0; off >>= 1) {
                pl += __shfl_xor(pl, off, 16);
                pr += __shfl_xor(pr, off, 16);
            }
            if ((lane & 15) == 0) {
                const int h = lane >> 4;
                el[nA * 4 + h] = pl;
                er[nA * 4 + h] = pr;
            }
        }
        if (hasB) {
            z[(size_t)nB * 64 + lane] = __float2half(accB);
            float pl = accB * a_l, pr = accB * a_r;
            #pragma unroll
            for (int off = 8; off > 0; off >>= 1) {
                pl += __shfl_xor(pl, off, 16);
                pr += __shfl_xor(pr, off, 16);
            }
            if ((lane & 15) == 0) {
                const int h = lane >> 4;
                el[nB * 4 + h] = pl;
                er[nB * 4 + h] = pr;
            }
        }
    }
}

// ---------------- Fused aggregation (1 node/wave, lean VGPR) ----------------
// Subgroup sg owns edges beg+sg, beg+sg+4, ...; unroll x4 -> 16 z-rows in
// flight per wave. No max pass. Epilogue: write relu(acc/den+b) to xout, or
// (layer 1) dot with preloaded 4-reg Wo quad -> zo[n].
__global__ __launch_bounds__(256) void k_csr_agg(
    const int* __restrict__ row_ptr, const int* __restrict__ ssrc,
    const float* __restrict__ el, const float* __restrict__ er,
    const __half* __restrict__ z, const float* __restrict__ b,
    float* __restrict__ xout,       // [NN][64] or nullptr
    const float* __restrict__ Wo,   // [64] (used when xout==nullptr)
    float* __restrict__ zo)         // [NN]  (used when xout==nullptr)
{
    const int t = threadIdx.x;
    const int wv = t >> 6, l = t & 63;
    const int sg = l >> 4, sl = l & 15, hh = sl >> 2;
    const int n = blockIdx.x * 4 + wv;
    const int beg = row_ptr[n], end = row_ptr[n + 1];
    const float er_hh = er[n * 4 + hh];

    float4 acc = {0.f, 0.f, 0.f, 0.f};
    float den = 0.f;
    int i = beg + sg;
    for (; i + 12 < end; i += 16) {
        const int s0 = ssrc[i], s1 = ssrc[i + 4];
        const int s2 = ssrc[i + 8], s3 = ssrc[i + 12];
        const float x0 = __expf(leaky02(el[s0 * 4 + hh] + er_hh));
        const float x1 = __expf(leaky02(el[s1 * 4 + hh] + er_hh));
        const float x2 = __expf(leaky02(el[s2 * 4 + hh] + er_hh));
        const float x3 = __expf(leaky02(el[s3 * 4 + hh] + er_hh));
        const uint2 r0 = *(const uint2*)(z + (size_t)s0 * 64 + sl * 4);
        const uint2 r1 = *(const uint2*)(z + (size_t)s1 * 64 + sl * 4);
        const uint2 r2 = *(const uint2*)(z + (size_t)s2 * 64 + sl * 4);
        const uint2 r3 = *(const uint2*)(z + (size_t)s3 * 64 + sl * 4);
        den += (x0 + x1) + (x2 + x3);
        float2 p;
        p = __half22float2(*(const __half2*)&r0.x); acc.x += x0 * p.x; acc.y += x0 * p.y;
        p = __half22float2(*(const __half2*)&r0.y); acc.z += x0 * p.x; acc.w += x0 * p.y;
        p = __half22float2(*(const __half2*)&r1.x); acc.x += x1 * p.x; acc.y += x1 * p.y;
        p = __half22float2(*(const __half2*)&r1.y); acc.z += x1 * p.x; acc.w += x1 * p.y;
        p = __half22float2(*(const __half2*)&r2.x); acc.x += x2 * p.x; acc.y += x2 * p.y;
        p = __half22float2(*(const __half2*)&r2.y); acc.z += x2 * p.x; acc.w += x2 * p.y;
        p = __half22float2(*(const __half2*)&r3.x); acc.x += x3 * p.x; acc.y += x3 * p.y;
        p = __half22float2(*(const __half2*)&r3.y); acc.z += x3 * p.x; acc.w += x3 * p.y;
    }
    for (; i < end; i += 4) {
        const int s0 = ssrc[i];
        const float x0 = __expf(leaky02(el[s0 * 4 + hh] + er_hh));
        const uint2 r0 = *(const uint2*)(z + (size_t)s0 * 64 + sl * 4);
        den += x0;
        float2 p;
        p = __half22float2(*(const __half2*)&r0.x); acc.x += x0 * p.x; acc.y += x0 * p.y;
        p = __half22float2(*(const __half2*)&r0.y); acc.z += x0 * p.x; acc.w += x0 * p.y;
    }

    // combine the 4 subgroups
    #pragma unroll
    for (int off = 16; off < 64; off <<= 1) {
        acc.x += __shfl_xor(acc.x, off, 64);
        acc.y += __shfl_xor(acc.y, off, 64);
        acc.z += __shfl_xor(acc.z, off, 64);
        acc.w += __shfl_xor(acc.w, off, 64);
        den   += __shfl_xor(den,   off, 64);
    }
    const float dinv = 1.0f / fmaxf(den, 1e-9f);

    const float4 b4 = *(const float4*)(b + sl * 4);
    float4 v;
    v.x = fmaxf(acc.x * dinv + b4.x, 0.f);
    v.y = fmaxf(acc.y * dinv + b4.y, 0.f);
    v.z = fmaxf(acc.z * dinv + b4.z, 0.f);
    v.w = fmaxf(acc.w * dinv + b4.w, 0.f);

    if (xout) {
        if (l < 16) *(float4*)(xout + (size_t)n * 64 + sl * 4) = v;
    } else {
        const float4 w4 = *(const float4*)(Wo + sl * 4);
        float p = v.x * w4.x + v.y * w4.y + v.z * w4.z + v.w * w4.w;
        #pragma unroll
        for (int off = 1; off < 16; off <<= 1) p += __shfl_xor(p, off, 64);
        if (l == 0) zo[n] = p;
    }
}

// ---------------- Output layer (H=1, D=1), single-pass, 16 lanes/node -------

__global__ __launch_bounds__(256) void k_csr_agg_o(
    const int* __restrict__ row_ptr, const int* __restrict__ ssrc,
    const float* __restrict__ zo, const float* __restrict__ alo,
    const float* __restrict__ aro, const float* __restrict__ bo,
    float* __restrict__ out)
{
    const int t = threadIdx.x, l = t & 15;
    const int n = blockIdx.x * 16 + (t >> 4);
    const float a = alo[0];
    const float zr = aro[0] * zo[n];
    const int beg = row_ptr[n], end = row_ptr[n + 1];

    float den = 0.f, accv = 0.f;
    for (int i = beg + l; i < end; i += 16) {
        const float zs = zo[ssrc[i]];
        const float ex = __expf(leaky02(a * zs + zr));
        den += ex; accv += ex * zs;
    }
    #pragma unroll
    for (int off = 8; off; off >>= 1) {
        den  += __shfl_xor(den, off, 16);
        accv += __shfl_xor(accv, off, 16);
    }
    if (l == 0) out[n] = accv / fmaxf(den, 1e-9f) + bo[0];
}

// ---------------- Launch ----------------

extern "C" void kernel_launch(void* const* d_in, const int* in_sizes, int n_in,
                              void* d_out, int out_size, void* d_ws, size_t ws_size,
                              hipStream_t stream) {
    const float* feat = (const float*)d_in[0];
    const int*   src  = (const int*)d_in[1];
    const int*   dst  = (const int*)d_in[2];
    const float* W0   = (const float*)d_in[3];
    const float* al0  = (const float*)d_in[4];
    const float* ar0  = (const float*)d_in[5];
    const float* b0   = (const float*)d_in[6];
    const float* W1   = (const float*)d_in[7];
    const float* al1  = (const float*)d_in[8];
    const float* ar1  = (const float*)d_in[9];
    const float* b1   = (const float*)d_in[10];
    const float* Wo   = (const float*)d_in[11];
    const float* alo  = (const float*)d_in[12];
    const float* aro  = (const float*)d_in[13];
    const float* bo   = (const float*)d_in[14];
    float* out = (float*)d_out;

    // workspace carve-up (int region padded so z/xA are 16B-aligned)
    int* bucketCnt  = (int*)d_ws;                   // [NBUK] (zeroed)
    int* row_ptr    = bucketCnt + NBUK;             // [NN+1]
    int* gBuf       = row_ptr + (NN + 2);           // [NBUK*CAP]
    int* ssrc       = gBuf + (size_t)NBUK * CAP;    // [NE]
    uintptr_t pa = ((uintptr_t)(ssrc + NE) + 15) & ~(uintptr_t)15;
    __half* z  = (__half*)pa;                       // [NN*64] fp16
    float* xA  = (float*)(z + (size_t)NN * 64);     // [NN*64]
    float* el  = xA + (size_t)NN * 64;              // [NN*4]
    float* er  = el + (size_t)NN * 4;               // [NN*4]
    float* zo  = er + (size_t)NN * 4;               // [NN]

    const int gBkt  = (NE + EPB - 1) / EPB;  // 391
    const int gPrep = (NN + 63) / 64;        // 1563
    const int gN16  = NN / 16;               // 6250
    const int gAgg  = NN / 4;                // 25000 (1 node/wave)

    // CSR build (LDS radix, 2 kernels + memset)
    hipMemsetAsync(bucketCnt, 0, NBUK * sizeof(int), stream);
    k_bucket   <<<gBkt, 256, 0, stream>>>(src, dst, bucketCnt, gBuf);
    k_csr_local<<<NBUK, 256, 0, stream>>>(bucketCnt, gBuf, row_ptr, ssrc);

    // Layer 0: feat -> xA
    k_node_prep<<<gPrep, 256, 0, stream>>>(feat, W0, al0, ar0, z, el, er);
    k_csr_agg  <<<gAgg, 256, 0, stream>>>(row_ptr, ssrc, el, er, z, b0,
                                          xA, nullptr, nullptr);

    // Layer 1: xA -> zo (output-layer GEMV fused into agg epilogue)
    k_node_prep<<<gPrep, 256, 0, stream>>>(xA, W1, al1, ar1, z, el, er);
    k_csr_agg  <<<gAgg, 256, 0, stream>>>(row_ptr, ssrc, el, er, z, b1,
                                          nullptr, Wo, zo);

    // Output layer
    k_csr_agg_o<<<gN16, 256, 0, stream>>>(row_ptr, ssrc, zo, alo, aro, bo, out);
}